// Round 5
// baseline (232.503 us; speedup 1.0000x reference)
//
#include <hip/hip_runtime.h>
#include <stdint.h>

// ---------------------------------------------------------------------------
// HopfieldAttention on MI355X (gfx950) -- round 5
//  round 4 + attn pipeline restructure (T3/T4):
//  - 2-deep prefetch into Kc[3]/Tc[4] LDS rings; per-chunk sync is
//    s_waitcnt vmcnt(4) + raw s_barrier (loads stay in flight across
//    barriers; vmcnt(0) only at the t=62 boundary).
//  - PV lagged one chunk: iter t = QK^T(t) || PV(t-1) || softmax(t);
//    breaks the serial per-chunk QK->SM->PV dependency chain.
//  - everything else (GEMMs, LN fusion, ktrans virtual-key permutation,
//    XCD-pinned swizzle, no-max softmax) unchanged from round 4.
// ---------------------------------------------------------------------------

#define DEV static __device__ __forceinline__

typedef __attribute__((ext_vector_type(8))) short short8;
typedef __attribute__((ext_vector_type(8))) __bf16 bf16x8;
typedef __attribute__((ext_vector_type(4))) float f32x4;
typedef __attribute__((ext_vector_type(16))) float f32x16;
typedef __attribute__((ext_vector_type(4))) unsigned int uint4v;

DEV unsigned short f2bf(float f) {
  unsigned int u = __builtin_bit_cast(unsigned int, f);
  u = u + 0x7fffu + ((u >> 16) & 1u);   // RNE
  return (unsigned short)(u >> 16);
}

DEV unsigned int cvtpk(float lo, float hi) {  // packed f32->bf16x2 (RNE)
  unsigned int r;
  asm("v_cvt_pk_bf16_f32 %0, %1, %2" : "=v"(r) : "v"(lo), "v"(hi));
  return r;
}

DEV f32x4 mfma16(short8 a, short8 b, f32x4 c) {
  return __builtin_amdgcn_mfma_f32_16x16x32_bf16(
      __builtin_bit_cast(bf16x8, a), __builtin_bit_cast(bf16x8, b), c, 0, 0, 0);
}

DEV f32x16 mfma32(short8 a, short8 b, f32x16 c) {
  return __builtin_amdgcn_mfma_f32_32x32x16_bf16(
      __builtin_bit_cast(bf16x8, a), __builtin_bit_cast(bf16x8, b), c, 0, 0, 0);
}

DEV f32x16 zero16() {
  f32x16 z;
#pragma unroll
  for (int i = 0; i < 16; ++i) z[i] = 0.f;
  return z;
}

DEV void gload16(void* lds, const void* g) {
  __builtin_amdgcn_global_load_lds(
      (const __attribute__((address_space(1))) void*)(uintptr_t)g,
      (__attribute__((address_space(3))) void*)(unsigned int)(uintptr_t)lds,
      16, 0, 0);
}

// ---------------------------------------------------------------------------
__global__ __launch_bounds__(256)
void xcast_kernel(const float* __restrict__ x, unsigned short* __restrict__ xbf) {
  int i = blockIdx.x * 256 + threadIdx.x;
  float4 v = ((const float4*)x)[i];
  ushort4 o;
  o.x = f2bf(v.x); o.y = f2bf(v.y); o.z = f2bf(v.z); o.w = f2bf(v.w);
  ((ushort4*)xbf)[i] = o;
}

__global__ __launch_bounds__(256)
void wtrans_kernel(const float* __restrict__ Wq, const float* __restrict__ Wk,
                   const float* __restrict__ Wv, const float* __restrict__ Wo,
                   unsigned short* __restrict__ wqkvT, unsigned short* __restrict__ woT) {
  __shared__ float t[64][65];
  int job = blockIdx.x;
  int wsel = job >> 6;
  int tile = job & 63;
  int tr = (tile >> 3) * 64;
  int tc = (tile & 7) * 64;
  const float* W = wsel == 0 ? Wq : wsel == 1 ? Wk : wsel == 2 ? Wv : Wo;
  unsigned short* T = wsel < 3 ? wqkvT + (size_t)wsel * 512 * 512 : woT;
  int lane = threadIdx.x & 63;
  int wv = threadIdx.x >> 6;
  for (int rr = 0; rr < 16; ++rr) {
    int r = wv * 16 + rr;
    t[r][lane] = W[(size_t)(tr + r) * 512 + tc + lane];
  }
  __syncthreads();
  for (int rr = 0; rr < 16; ++rr) {
    int r = wv * 16 + rr;
    T[(size_t)(tc + r) * 512 + tr + lane] = f2bf(t[lane][r]);
  }
}

// ---------------------------------------------------------------------------
// GEMM 128x128 tile, BK=64, 2-phase staging (unchanged).
template <int MODE>
__global__ __launch_bounds__(256, 2)
void gemm_kernel(const unsigned short* __restrict__ A,
                 const unsigned short* __restrict__ WT,
                 const float* __restrict__ b0, const float* __restrict__ b1,
                 const float* __restrict__ b2,
                 const float* __restrict__ gamma, const float* __restrict__ beta,
                 unsigned short* __restrict__ Qo, unsigned short* __restrict__ Ko,
                 unsigned short* __restrict__ Vo, float* __restrict__ Fo) {
  __shared__ __align__(16) unsigned char As[2][16384];
  __shared__ __align__(16) unsigned char Ws[2][16384];

  const int tid = threadIdx.x;
  const int lane = tid & 63;
  const int w = tid >> 6;
  const int l15 = lane & 15;
  const int l4 = lane >> 4;
  const int m0 = blockIdx.x * 128;
  const int by = blockIdx.y;
  const int wm = (w >> 1) * 64;
  const int wn = (w & 1) * 64;

  f32x4 acc[4][4];
#pragma unroll
  for (int mt = 0; mt < 4; ++mt)
#pragma unroll
    for (int nt = 0; nt < 4; ++nt) acc[mt][nt] = (f32x4){0.f, 0.f, 0.f, 0.f};

  auto stage = [&](int i) {
    int buf = i & 1;
    int k0 = i * 64;
#pragma unroll
    for (int it = 0; it < 4; ++it) {
      int idx = it * 256 + tid;
      int row = idx >> 3;
      int sc = ((idx & 7) * 16) ^ ((row & 7) << 4);
      gload16(As[buf] + idx * 16,
              (const unsigned char*)A + ((size_t)(m0 + row) * 512 + k0) * 2 + sc);
      gload16(Ws[buf] + idx * 16,
              (const unsigned char*)WT + ((size_t)(by * 128 + row) * 512 + k0) * 2 + sc);
    }
  };

  stage(0);
  __syncthreads();

  for (int i = 0; i < 8; ++i) {
    int buf = i & 1;
    if (i < 7) stage(i + 1);
    __builtin_amdgcn_s_setprio(1);
#pragma unroll
    for (int kk = 0; kk < 2; ++kk) {
      short8 af[4], bfr[4];
#pragma unroll
      for (int mt = 0; mt < 4; ++mt) {
        int row = wm + mt * 16 + l15;
        int colb = (l4 * 16 + kk * 64) ^ ((row & 7) << 4);
        af[mt] = *(const short8*)(As[buf] + row * 128 + colb);
      }
#pragma unroll
      for (int nt = 0; nt < 4; ++nt) {
        int row = wn + nt * 16 + l15;
        int colb = (l4 * 16 + kk * 64) ^ ((row & 7) << 4);
        bfr[nt] = *(const short8*)(Ws[buf] + row * 128 + colb);
      }
#pragma unroll
      for (int mt = 0; mt < 4; ++mt)
#pragma unroll
        for (int nt = 0; nt < 4; ++nt) acc[mt][nt] = mfma16(af[mt], bfr[nt], acc[mt][nt]);
    }
    __builtin_amdgcn_s_setprio(0);
    __syncthreads();
  }

  const float cs = 1.4426950408889634f / 8.0f;
  const float* bias = (MODE == 1) ? b0 : (by >> 2) == 0 ? b0 : (by >> 2) == 1 ? b1 : b2;
  float bvv[4];
#pragma unroll
  for (int nt = 0; nt < 4; ++nt) bvv[nt] = bias[(by & 3) * 128 + wn + nt * 16 + l15];

  if (MODE == 1) {
#pragma unroll
    for (int mt = 0; mt < 4; ++mt)
#pragma unroll
      for (int r = 0; r < 4; ++r) {
        int gr = m0 + wm + mt * 16 + l4 * 4 + r;
#pragma unroll
        for (int nt = 0; nt < 4; ++nt)
          Fo[(size_t)gr * 512 + (by & 3) * 128 + wn + nt * 16 + l15] =
              acc[mt][nt][r] + bvv[nt];
      }
  } else {
    const int seg = by >> 2;
    const int h = (by & 3) * 2 + (wn >> 6);
    if (seg == 2) {
#pragma unroll
      for (int mt = 0; mt < 4; ++mt)
#pragma unroll
        for (int r = 0; r < 4; ++r) {
          int gr = m0 + wm + mt * 16 + l4 * 4 + r;
          int b = gr >> 10, s = gr & 1023;
          size_t base = ((size_t)(b * 8 + h) << 16) + ((size_t)s << 6);
#pragma unroll
          for (int nt = 0; nt < 4; ++nt)
            Vo[base + nt * 16 + l15] = f2bf(acc[mt][nt][r] + bvv[nt]);
        }
    } else {
      float g4[4], be4[4];
#pragma unroll
      for (int nt = 0; nt < 4; ++nt) {
        g4[nt] = gamma[nt * 16 + l15];
        be4[nt] = beta[nt * 16 + l15];
      }
      unsigned short* dst = seg == 0 ? Qo : Ko;
      const float m = seg == 0 ? cs : 1.0f;
#pragma unroll
      for (int mt = 0; mt < 4; ++mt)
#pragma unroll
        for (int r = 0; r < 4; ++r) {
          float v[4];
#pragma unroll
          for (int nt = 0; nt < 4; ++nt) v[nt] = acc[mt][nt][r] + bvv[nt];
          float s1 = (v[0] + v[1]) + (v[2] + v[3]);
          s1 += __shfl_xor(s1, 1); s1 += __shfl_xor(s1, 2);
          s1 += __shfl_xor(s1, 4); s1 += __shfl_xor(s1, 8);
          float mu = s1 * (1.0f / 64.0f);
          float s2 = v[0]*v[0] + v[1]*v[1] + v[2]*v[2] + v[3]*v[3];
          s2 += __shfl_xor(s2, 1); s2 += __shfl_xor(s2, 2);
          s2 += __shfl_xor(s2, 4); s2 += __shfl_xor(s2, 8);
          float var = s2 * (1.0f / 64.0f) - mu * mu;
          float rs = rsqrtf(var + 1e-5f);
          int gr = m0 + wm + mt * 16 + l4 * 4 + r;
          int b = gr >> 10, s = gr & 1023;
          size_t base = ((size_t)(b * 8 + h) << 16) + ((size_t)s << 6);
#pragma unroll
          for (int nt = 0; nt < 4; ++nt) {
            float y = ((v[nt] - mu) * rs * g4[nt] + be4[nt]) * m;
            dst[base + nt * 16 + l15] = f2bf(y);
          }
        }
    }
  }
}

// ---------------------------------------------------------------------------
// K/V transpose with 32x32-MFMA virtual-key permutation (unchanged).
__global__ __launch_bounds__(256)
void ktrans_kernel(const unsigned short* __restrict__ Kb,
                   const unsigned short* __restrict__ Vb,
                   unsigned short* __restrict__ KTg, unsigned short* __restrict__ VTg) {
  __shared__ unsigned short tile[64][65];
  const int c = blockIdx.x;
  const int bh = blockIdx.y;
  const unsigned short* src = blockIdx.z ? Vb : Kb;
  unsigned short* dst = blockIdx.z ? VTg : KTg;
  const int t = threadIdx.x;
  {
    int j = t >> 2, c16 = (t & 3) * 16;
    const unsigned short* sp = src + ((size_t)bh << 16) + ((size_t)(c * 64 + j) << 6) + c16;
    unsigned short vals[16];
    *(uint4*)(vals) = *(const uint4*)(sp);
    *(uint4*)(vals + 8) = *(const uint4*)(sp + 8);
#pragma unroll
    for (int i = 0; i < 16; ++i) tile[j][c16 + i] = vals[i];
  }
  __syncthreads();
  {
    int d = t >> 2, k16 = (t & 3) * 16;
    unsigned short ov[16];
#pragma unroll
    for (int i = 0; i < 16; ++i) {
      int kp = k16 + i;
      int g = kp >> 5, r5 = kp & 31;
      int c16 = r5 >> 4, h = (r5 >> 3) & 1, ii = r5 & 7;
      int phys = g * 32 + c16 * 16 + 8 * (ii >> 2) + 4 * h + (ii & 3);
      ov[i] = tile[phys][d];
    }
    unsigned short* dp = dst + ((size_t)bh << 16) + ((size_t)d << 10) + c * 64 + k16;
    *(uint4*)(dp) = *(uint4*)(ov);
    *(uint4*)(dp + 8) = *(uint4*)(ov + 8);
  }
}

// ---------------------------------------------------------------------------
// attn: 4 flash passes, 4 waves x 32 q-rows, KVBLK=64, mfma 32x32x16,
// counted-vmcnt pipeline with lagged PV.
__global__ __launch_bounds__(256, 2)
void attn_kernel(const unsigned short* __restrict__ Qb,
                 const unsigned short* __restrict__ Kb,
                 const unsigned short* __restrict__ KTg,
                 const unsigned short* __restrict__ VTg,
                 unsigned short* __restrict__ Ob) {
  __shared__ __align__(16) unsigned char Kc[3][8192];   // [key64][d64] swizzled
  __shared__ __align__(16) unsigned char Tc[4][8192];   // [d64][vkey64] swizzled

  const int tid = threadIdx.x;
  const int lane = tid & 63;
  const int w = tid >> 6;
  const int l31 = lane & 31;
  const int hi = lane >> 5;
  // XCD-pinned swizzle: all 8 q-tiles of a bh on the same XCD.
  const int bi = blockIdx.x;
  const int xcd = bi & 7, wnd = bi >> 3;
  const int bh = xcd * 8 + (wnd & 7);
  const int qt = wnd >> 3;
  const int q0 = qt * 128 + w * 32;
  const size_t kvb = (size_t)bh << 17;   // byte offset of bh (1024*64*2)
  const float cs = 1.4426950408889634f / 8.0f;

  int sOffK[2], sOffT[2];
#pragma unroll
  for (int it = 0; it < 2; ++it) {
    int idx = it * 256 + tid;
    int row = idx >> 3;
    int colb = ((idx & 7) * 16) ^ ((row & 7) << 4);
    sOffK[it] = row * 128 + colb;
    sOffT[it] = row * 2048 + colb;
  }
  const unsigned char* kS = (const unsigned char*)Kb + kvb;
  const unsigned char* tKS = (const unsigned char*)KTg + kvb;
  const unsigned char* tVS = (const unsigned char*)VTg + kvb;

  auto stage = [&](int t) {
    int c = t & 15;
    const unsigned char* ts = (t >= 48) ? tVS : tKS;
    unsigned char* kd = Kc[t % 3];
    unsigned char* td = Tc[t & 3];
#pragma unroll
    for (int it = 0; it < 2; ++it) {
      int idx = it * 256 + tid;
      gload16(kd + idx * 16, kS + (size_t)c * 8192 + sOffK[it]);
      gload16(td + idx * 16, ts + (size_t)c * 128 + sOffT[it]);
    }
  };

  // Q fragments: qf[s] elem i = Q[q=l31][16s + 8hi + i]
  short8 qf[4];
  {
    const unsigned char* qp =
        (const unsigned char*)Qb + kvb + ((size_t)(q0 + l31) << 7) + hi * 16;
    qf[0] = *(const short8*)(qp);
    qf[1] = *(const short8*)(qp + 32);
    qf[2] = *(const short8*)(qp + 64);
    qf[3] = *(const short8*)(qp + 96);
  }

  stage(0);
  stage(1);
  asm volatile("s_waitcnt vmcnt(4)" ::: "memory");
  __builtin_amdgcn_s_barrier();
  __builtin_amdgcn_sched_barrier(0);

  f32x16 acc0 = zero16(), acc1 = zero16();
  float lsum = 0.f;
  const int sw = (l31 & 7) << 4;
  const int hb = hi * 16;
  const int rowA = l31 * 128;

  short8 p0, p1, p2, p3;   // P frags of chunk t (written by SM, read by lagged PV)

  auto PV = [&](int bufT) {
    const unsigned char* TB = Tc[bufT];
    short8 t0, t1;
    t0 = *(const short8*)(TB + rowA + ((0 + hb) ^ sw));
    t1 = *(const short8*)(TB + 4096 + rowA + ((0 + hb) ^ sw));
    acc0 = mfma32(t0, p0, acc0);
    acc1 = mfma32(t1, p0, acc1);
    t0 = *(const short8*)(TB + rowA + ((32 + hb) ^ sw));
    t1 = *(const short8*)(TB + 4096 + rowA + ((32 + hb) ^ sw));
    acc0 = mfma32(t0, p1, acc0);
    acc1 = mfma32(t1, p1, acc1);
    t0 = *(const short8*)(TB + rowA + ((64 + hb) ^ sw));
    t1 = *(const short8*)(TB + 4096 + rowA + ((64 + hb) ^ sw));
    acc0 = mfma32(t0, p2, acc0);
    acc1 = mfma32(t1, p2, acc1);
    t0 = *(const short8*)(TB + rowA + ((96 + hb) ^ sw));
    t1 = *(const short8*)(TB + 4096 + rowA + ((96 + hb) ^ sw));
    acc0 = mfma32(t0, p3, acc0);
    acc1 = mfma32(t1, p3, acc1);
  };

  for (int t = 0; t < 64; ++t) {
    const int c = t & 15;
    if (t + 2 < 64) stage(t + 2);

    // ---- QK^T(t): S^T = K Q^T from Kc[t%3] ----
    f32x16 s0 = zero16(), s1 = zero16();
    {
      const unsigned char* KB = Kc[t % 3];
      short8 kfa[4], kfb[4];
#pragma unroll
      for (int s = 0; s < 4; ++s) {
        int cb = (32 * s + hb) ^ sw;
        kfa[s] = *(const short8*)(KB + rowA + cb);
        kfb[s] = *(const short8*)(KB + 4096 + rowA + cb);
      }
      __builtin_amdgcn_s_setprio(1);
#pragma unroll
      for (int s = 0; s < 4; ++s) {
        s0 = mfma32(kfa[s], qf[s], s0);
        s1 = mfma32(kfb[s], qf[s], s1);
      }
      __builtin_amdgcn_s_setprio(0);
    }

    // ---- PV(t-1) from Tc[(t-1)&3] (skipped at pass starts) ----
    if (c > 0) {
      __builtin_amdgcn_s_setprio(1);
      PV((t - 1) & 3);
      __builtin_amdgcn_s_setprio(0);
    }

    // ---- SM(t): p = exp2(s), pack to bf16 B-frags ----
    {
      unsigned int u0[8], u1[8];
#pragma unroll
      for (int r = 0; r < 16; r += 2) {
        float pA = exp2f(s0[r]), pB = exp2f(s0[r + 1]);
        lsum += pA + pB;
        u0[r >> 1] = cvtpk(pA, pB);
      }
#pragma unroll
      for (int r = 0; r < 16; r += 2) {
        float pA = exp2f(s1[r]), pB = exp2f(s1[r + 1]);
        lsum += pA + pB;
        u1[r >> 1] = cvtpk(pA, pB);
      }
      p0 = __builtin_bit_cast(short8, (uint4v){u0[0], u0[1], u0[2], u0[3]});
      p1 = __builtin_bit_cast(short8, (uint4v){u0[4], u0[5], u0[6], u0[7]});
      p2 = __builtin_bit_cast(short8, (uint4v){u1[0], u1[1], u1[2], u1[3]});
      p3 = __builtin_bit_cast(short8, (uint4v){u1[4], u1[5], u1[6], u1[7]});
    }

    if (c == 15) {
      // drain the pipeline: PV(t) now
      __builtin_amdgcn_s_setprio(1);
      PV(t & 3);
      __builtin_amdgcn_s_setprio(0);
      // ---- pass end ----
      lsum += __shfl_xor(lsum, 32);
      if (t < 63) {
        float f = cs / lsum;
#pragma unroll
        for (int s = 0; s < 4; ++s) {
          const f32x16& A = (s >> 1) ? acc1 : acc0;
          const int base = 8 * (s & 1);
          float a0 = A[base] * f, a1 = A[base + 1] * f;
          float a2 = A[base + 2] * f, a3 = A[base + 3] * f;
          float b0 = A[base + 4] * f, b1 = A[base + 5] * f;
          float b2 = A[base + 6] * f, b3 = A[base + 7] * f;
          float s0_ = hi ? a0 : b0, s1_ = hi ? a1 : b1;
          float s2_ = hi ? a2 : b2, s3_ = hi ? a3 : b3;
          float r0 = __shfl_xor(s0_, 32), r1 = __shfl_xor(s1_, 32);
          float r2 = __shfl_xor(s2_, 32), r3 = __shfl_xor(s3_, 32);
          float e0 = hi ? r0 : a0, e1 = hi ? r1 : a1;
          float e2 = hi ? r2 : a2, e3 = hi ? r3 : a3;
          float e4 = hi ? b0 : r0, e5 = hi ? b1 : r1;
          float e6 = hi ? b2 : r2, e7 = hi ? b3 : r3;
          qf[s] = __builtin_bit_cast(
              short8, (uint4v){cvtpk(e0, e1), cvtpk(e2, e3), cvtpk(e4, e5), cvtpk(e6, e7)});
        }
        acc0 = zero16();
        acc1 = zero16();
        lsum = 0.f;
      } else {
        float inv = 1.0f / lsum;
        const int b = bh >> 3, h = bh & 7;
        const int qg = q0 + l31;
        unsigned short* orow = Ob + ((size_t)(b * 1024 + qg) << 9) + h * 64;
#pragma unroll
        for (int dt = 0; dt < 2; ++dt) {
          const f32x16& A = dt ? acc1 : acc0;
#pragma unroll
          for (int rq = 0; rq < 4; ++rq) {
            ushort4 o;
            o.x = f2bf(A[4 * rq + 0] * inv);
            o.y = f2bf(A[4 * rq + 1] * inv);
            o.z = f2bf(A[4 * rq + 2] * inv);
            o.w = f2bf(A[4 * rq + 3] * inv);
            *(ushort4*)(orow + dt * 32 + 8 * rq + 4 * hi) = o;
          }
        }
      }
    }

    if (t < 63) {
      if (t == 62) {
        asm volatile("s_waitcnt vmcnt(0)" ::: "memory");
      } else {
        asm volatile("s_waitcnt vmcnt(4)" ::: "memory");
      }
      __builtin_amdgcn_s_barrier();
      __builtin_amdgcn_sched_barrier(0);
    }
  }
}

// ---------------------------------------------------------------------------
extern "C" void kernel_launch(void* const* d_in, const int* in_sizes, int n_in,
                              void* d_out, int out_size, void* d_ws, size_t ws_size,
                              hipStream_t stream) {
  const float* x  = (const float*)d_in[0];
  const float* Wq = (const float*)d_in[1];
  const float* bq = (const float*)d_in[2];
  const float* Wk = (const float*)d_in[3];
  const float* bk = (const float*)d_in[4];
  const float* Wv = (const float*)d_in[5];
  const float* bv = (const float*)d_in[6];
  const float* Wo = (const float*)d_in[7];
  const float* bo = (const float*)d_in[8];
  const float* gamma = (const float*)d_in[9];
  const float* beta  = (const float*)d_in[10];
  (void)in_sizes; (void)n_in; (void)out_size; (void)ws_size;

  char* ws = (char*)d_ws;
  size_t off = 0;
  auto alloc = [&](size_t bytes) {
    char* p = ws + off;
    off += (bytes + 255) & ~(size_t)255;
    return p;
  };
  unsigned short* xbf   = (unsigned short*)alloc(8192ull * 512 * 2);
  unsigned short* wqkvT = (unsigned short*)alloc(1536ull * 512 * 2);
  unsigned short* woT   = (unsigned short*)alloc(512ull * 512 * 2);
  unsigned short* Qbf   = (unsigned short*)alloc(64ull * 1024 * 64 * 2);
  unsigned short* Kbf   = (unsigned short*)alloc(64ull * 1024 * 64 * 2);
  unsigned short* Vbf   = (unsigned short*)alloc(64ull * 1024 * 64 * 2);
  unsigned short* KTg   = (unsigned short*)alloc(64ull * 1024 * 64 * 2);
  unsigned short* VTg   = (unsigned short*)alloc(64ull * 1024 * 64 * 2);
  unsigned short* Obf   = (unsigned short*)alloc(8192ull * 512 * 2);

  xcast_kernel<<<4096, 256, 0, stream>>>(x, xbf);
  wtrans_kernel<<<256, 256, 0, stream>>>(Wq, Wk, Wv, Wo, wqkvT, woT);

  gemm_kernel<0><<<dim3(64, 12), 256, 0, stream>>>(
      xbf, wqkvT, bq, bk, bv, gamma, beta, Qbf, Kbf, Vbf, nullptr);

  ktrans_kernel<<<dim3(16, 64, 2), 256, 0, stream>>>(Kbf, Vbf, KTg, VTg);

  attn_kernel<<<512, 256, 0, stream>>>(Qbf, Kbf, KTg, VTg, Obf);

  gemm_kernel<1><<<dim3(64, 4), 256, 0, stream>>>(
      Obf, woT, bo, nullptr, nullptr, nullptr, nullptr,
      nullptr, nullptr, nullptr, (float*)d_out);
}